// Round 6
// baseline (727.823 us; speedup 1.0000x reference)
//
#include <hip/hip_runtime.h>
#include <cstdint>
#include <cstddef>

#define B_ 2048
#define N_ 62
#define FIN_ 128
#define HID_ 512
#define HEADS_ 8
#define FOUT_ 64
#define LAYERS_ 3
#define M_ (B_*N_)

typedef __bf16 bf16x8 __attribute__((ext_vector_type(8)));
typedef __bf16 bf16x4 __attribute__((ext_vector_type(4)));
typedef float  f32x4  __attribute__((ext_vector_type(4)));
typedef unsigned short u16;

#define LOG2E 1.4426950408889634f

#if __has_builtin(__builtin_amdgcn_exp2f)
#define EXP2F(x) __builtin_amdgcn_exp2f(x)
#else
#define EXP2F(x) exp2f(x)
#endif
#if __has_builtin(__builtin_amdgcn_logf)
#define LOG2F(x) __builtin_amdgcn_logf(x)
#else
#define LOG2F(x) log2f(x)
#endif

static __device__ __forceinline__ u16 f2bf(float f) {
    union { float f; uint32_t u; } v; v.f = f;
    uint32_t u = v.u;
    return (u16)((u + 0x7fffu + ((u >> 16) & 1u)) >> 16);
}
static __device__ __forceinline__ float bf2f(u16 s) {
    union { uint32_t u; float f; } v; v.u = ((uint32_t)s) << 16;
    return v.f;
}
static __device__ __forceinline__ float rdlane(float v, int l) {
    union { float f; int i; } a, b; a.f = v;
    b.i = __builtin_amdgcn_readlane(a.i, l);
    return b.f;
}
// compiler-friendly pack: emits v_cvt_pk_bf16_f32 pairs (RNE)
static __device__ __forceinline__ bf16x4 pack4(f32x4 v) {
    bf16x4 o;
    o[0] = (__bf16)v[0]; o[1] = (__bf16)v[1];
    o[2] = (__bf16)v[2]; o[3] = (__bf16)v[3];
    return o;
}

// ---------------------------------------------------------------------------
// Pack weights:
//  wmlp_t[n][k]  (n = feature 0..511, k = 0..127), bf16
//  wgat2[l][h][80][512]: rows 0..63 = W_head^T (row d, col k),
//    row 64 = log2e * (W_head @ a1), row 65 = log2e * (W_head @ a2),
//    rows 66..79 = 0.
// ---------------------------------------------------------------------------
__global__ __launch_bounds__(256) void repack_w(
    const float* __restrict__ Wm, const float* __restrict__ Wg,
    const float* __restrict__ ag,
    u16* __restrict__ wmlp_t, u16* __restrict__ wgat2)
{
    int idx = blockIdx.x * 256 + threadIdx.x;
    const int T1 = HID_ * FIN_;                    // 65536
    const int T2 = LAYERS_ * HEADS_ * 80 * HID_;   // 983040
    if (idx < T1) {
        int n = idx / FIN_, k = idx % FIN_;
        wmlp_t[idx] = f2bf(Wm[k * HID_ + n]);
    } else if (idx < T1 + T2) {
        int j = idx - T1;
        int lh = j / (80 * HID_);
        int r  = j % (80 * HID_);
        int n = r / HID_, k = r % HID_;
        float v;
        if (n < 64) {
            v = Wg[((size_t)lh * HID_ + k) * FOUT_ + n];
        } else if (n < 66) {
            const float* ap = ag + (size_t)lh * 128 + (n - 64) * 64;
            const float* wrow = Wg + ((size_t)lh * HID_ + k) * FOUT_;
            float s = 0.f;
            for (int d = 0; d < 64; d++) s += wrow[d] * ap[d];
            v = s * LOG2E;
        } else {
            v = 0.f;
        }
        wgat2[j] = f2bf(v);
    }
}

// ---------------------------------------------------------------------------
// adjacency -> per-row 64-bit masks + transposed (per-column) masks
// ---------------------------------------------------------------------------
__global__ __launch_bounds__(256) void build_masks(
    const int* __restrict__ adj, uint64_t* __restrict__ masks,
    uint64_t* __restrict__ masksT)
{
    __shared__ uint32_t m32[128];
    const int b = blockIdx.x, tid = threadIdx.x;
    if (tid < 128) m32[tid] = 0;
    __syncthreads();
    const int* a = adj + (size_t)b * N_ * N_;
    for (int idx = tid; idx < N_ * N_; idx += 256) {
        int i = idx / N_, j = idx % N_;
        if (a[idx] > 0) atomicOr(&m32[i * 2 + (j >> 5)], 1u << (j & 31));
    }
    __syncthreads();
    if (tid < 128) ((uint32_t*)(masks + (size_t)b * 64))[tid] = m32[tid];
    if (tid < 64) {
        int j = tid;
        uint64_t c = 0;
        for (int i = 0; i < N_; i++) {
            uint64_t bit = (m32[i * 2 + (j >> 5)] >> (j & 31)) & 1u;
            c |= bit << i;
        }
        masksT[(size_t)b * 64 + j] = c;
    }
}

// ---------------------------------------------------------------------------
// Fully fused network, one block per graph, wave = head.
// LDS buf = 8 wave-private regions of [64][72] u16 (9216 B each):
//   region w holds hin feature-block w (node-major) before bar(A), and
//   wave w's hT (feature-major) + hout block after bar(A). Because hT/PV/
//   ELU touch ONLY the own region, the old bar(B) is gone: 2 barriers/layer.
// All f32->bf16 conversions are (__bf16) casts (v_cvt_pk_bf16_f32), not
// manual bit-rounding (round-5 post-mortem: ~600 VALU/wave/layer wasted).
// ---------------------------------------------------------------------------
#define S_R  72      // u16 stride inside a region
#define RSZ  4608    // u16 size of a region (64*72)
#define S_X  136     // u16 stride for x-stage [64][S_X]
#define X0   27648   // u16 offset of x-stage (regions 6,7)

__global__ __launch_bounds__(512, 4) void gat_fused(
    const float* __restrict__ x,
    const float* __restrict__ bng, const float* __restrict__ bnb,
    const float* __restrict__ bnm, const float* __restrict__ bnv,
    const u16* __restrict__ wmlp_t, const float* __restrict__ bm,
    const u16* __restrict__ wgat2,
    const uint64_t* __restrict__ masks, const uint64_t* __restrict__ masksT,
    const float* __restrict__ Wout, const float* __restrict__ bout,
    float* __restrict__ out)
{
    __shared__ __align__(16) u16 buf[36864];
    __shared__ uint64_t msk[64];
    __shared__ __align__(16) float fstat[1544];
    float* F1 = fstat;          // [8][64] f1 per (head, j)  (log2e-scaled)
    float* F2 = fstat + 512;    // [8][64] f2 per (head, i)
    float* LS = fstat + 1024;   // [8][64] m + log2(s) per (head, j)

    const int tid = threadIdx.x, b = blockIdx.x;
    const int wave = tid >> 6, lane = tid & 63;
    const int lr = lane & 15, lq = lane >> 4;
    const int w64 = wave * 64;
    const int wreg = wave * RSZ;

    // per-lane transposed column mask (bit i = adj[i][lane])
    const uint64_t cm = masksT[(size_t)b * 64 + lane];
    const uint32_t cml = (uint32_t)cm, cmh = (uint32_t)(cm >> 32);

    // ---- stage BN(x) -> xs bf16 [64][136] (rows 62,63 zero); stage msk ----
    {
        const float* xg = x + (size_t)b * N_ * FIN_;
        for (int idx = tid; idx < 2048; idx += 512) {
            int n = idx >> 5, kq = idx & 31;
            bf16x4 o = {(__bf16)0.f, (__bf16)0.f, (__bf16)0.f, (__bf16)0.f};
            if (n < N_) {
                float s = bng[n] * rsqrtf(bnv[n] + 1e-5f);
                float sh = bnb[n] - bnm[n] * s;
                float4 v = *(const float4*)(xg + n * FIN_ + kq * 4);
                o[0] = (__bf16)(v.x * s + sh); o[1] = (__bf16)(v.y * s + sh);
                o[2] = (__bf16)(v.z * s + sh); o[3] = (__bf16)(v.w * s + sh);
            }
            *(bf16x4*)&buf[X0 + n * S_X + kq * 4] = o;
        }
        if (tid < 64) msk[tid] = (tid < N_) ? masks[(size_t)b * 64 + tid] : 0ull;
    }
    __syncthreads();

    // ---- MLP (operand-swapped): C[feature][node]; feature block w -> region w
    {
        f32x4 acc[4][4];
#pragma unroll
        for (int mt = 0; mt < 4; mt++)
#pragma unroll
            for (int nt = 0; nt < 4; nt++) acc[mt][nt] = (f32x4){0.f, 0.f, 0.f, 0.f};
        const int c0 = w64;
#pragma unroll
        for (int kt = 0; kt < 4; kt++) {
            int k0 = kt * 32;
            bf16x8 xf[4];
#pragma unroll
            for (int nt = 0; nt < 4; nt++)
                xf[nt] = *(const bf16x8*)&buf[X0 + (nt * 16 + lr) * S_X + k0 + lq * 8];
#pragma unroll
            for (int mt = 0; mt < 4; mt++) {
                bf16x8 wf = *(const bf16x8*)(wmlp_t + (size_t)(c0 + mt * 16 + lr) * FIN_ + k0 + lq * 8);
#pragma unroll
                for (int nt = 0; nt < 4; nt++)
                    acc[mt][nt] = __builtin_amdgcn_mfma_f32_16x16x32_bf16(
                        wf, xf[nt], acc[mt][nt], 0, 0, 0);
            }
        }
        __syncthreads();   // xs reads done before region writes (waves 6,7 alias xs)
        f32x4 bl[4];
#pragma unroll
        for (int mt = 0; mt < 4; mt++)
            bl[mt] = *(const f32x4*)&bm[c0 + mt * 16 + lq * 4];
#pragma unroll
        for (int mt = 0; mt < 4; mt++)
#pragma unroll
            for (int nt = 0; nt < 4; nt++) {
                int node = nt * 16 + lr;
                if (node < N_)
                    *(bf16x4*)&buf[wreg + node * S_R + mt * 16 + lq * 4] =
                        pack4(acc[mt][nt] + bl[mt]);
            }
        // zero pad rows 62,63 of own region
        if (lane < 16) {
            uint4 z = {0u, 0u, 0u, 0u};
            *(uint4*)&buf[wreg + (N_ + (lane >> 3)) * S_R + (lane & 7) * 8] = z;
        }
    }
    __syncthreads();

    // ---- GAT layers ----
#pragma unroll 1
    for (int l = 0; l < LAYERS_; l++) {
        const u16* wp = wgat2 + (size_t)(l * HEADS_ + wave) * 80 * HID_;

        // ---- f-pass: [64x512] @ [512x16] (wa rows 64/65); 16 acc regs ----
        {
            f32x4 accf[4];
#pragma unroll
            for (int mt = 0; mt < 4; mt++) accf[mt] = (f32x4){0.f, 0.f, 0.f, 0.f};
#pragma unroll 4
            for (int kt = 0; kt < 16; kt++) {
                int koff = (kt >> 1) * RSZ + (kt & 1) * 32 + lq * 8;
                bf16x8 bfr = *(const bf16x8*)(wp + (size_t)(64 + lr) * HID_ + kt * 32 + lq * 8);
#pragma unroll
                for (int mt = 0; mt < 4; mt++) {
                    bf16x8 af = *(const bf16x8*)&buf[koff + (mt * 16 + lr) * S_R];
                    accf[mt] = __builtin_amdgcn_mfma_f32_16x16x32_bf16(
                        af, bfr, accf[mt], 0, 0, 0);
                }
            }
            if (lr < 2) {
                float* Fp = lr ? F2 : F1;
#pragma unroll
                for (int mt = 0; mt < 4; mt++)
#pragma unroll
                    for (int r = 0; r < 4; r++)
                        Fp[w64 + mt * 16 + lq * 4 + r] = accf[mt][r];
            }
        }

        // ---- stats (wave-local: own F1/F2 -> own LS) ----
        {
            float p1 = F1[w64 + lane];
            float p2 = F2[w64 + lane];
            // m_j = leaky(max_all_i f2_i + f1_j): upper bound, exact for
            // softmax (m-invariance). 6-step wave max.
            float pm = (lane < N_) ? p2 : -3.0e38f;
#pragma unroll
            for (int off = 32; off; off >>= 1) pm = fmaxf(pm, __shfl_xor(pm, off, 64));
            float vm = pm + p1;
            float m = fmaxf(vm, 0.2f * vm);
            float s0 = 0.f, s1 = 0.f;
#pragma unroll
            for (int i = 0; i < N_; i += 2) {
                float fa = rdlane(p2, i), fb = rdlane(p2, i + 1);
                float va = fa + p1, vb = fb + p1;
                va = fmaxf(va, 0.2f * va); vb = fmaxf(vb, 0.2f * vb);
                float ea = EXP2F(va - m), eb = EXP2F(vb - m);
                uint32_t w = (i < 32) ? cml : cmh;
                s0 += ((w >> (i & 31)) & 1u) ? ea : 0.f;
                s1 += ((w >> ((i + 1) & 31)) & 1u) ? eb : 0.f;
            }
            float ssum = fmaxf(s0 + s1, 1e-35f);
            LS[w64 + lane] = m + LOG2F(ssum);   // p = exp2(e - LS)
        }

        // ---- main projection: h = hin @ W_head (64x512 @ 512x64) ----
        f32x4 acc[4][4];
#pragma unroll
        for (int mt = 0; mt < 4; mt++)
#pragma unroll
            for (int nt = 0; nt < 4; nt++) acc[mt][nt] = (f32x4){0.f, 0.f, 0.f, 0.f};
#pragma unroll 4
        for (int kt = 0; kt < 16; kt++) {
            int koff = (kt >> 1) * RSZ + (kt & 1) * 32 + lq * 8;
            bf16x8 af[4];
#pragma unroll
            for (int mt = 0; mt < 4; mt++)
                af[mt] = *(const bf16x8*)&buf[koff + (mt * 16 + lr) * S_R];
#pragma unroll
            for (int nt = 0; nt < 4; nt++) {
                bf16x8 bfr = *(const bf16x8*)(wp + (size_t)(nt * 16 + lr) * HID_ + kt * 32 + lq * 8);
#pragma unroll
                for (int mt = 0; mt < 4; mt++)
                    acc[mt][nt] = __builtin_amdgcn_mfma_f32_16x16x32_bf16(
                        af[mt], bfr, acc[mt][nt], 0, 0, 0);
            }
        }

        __syncthreads();   // (A) all hin reads done -> regions become wave-private

        // transpose-store h -> own region as hT[d_local][j] (stride 72)
#pragma unroll
        for (int mt = 0; mt < 4; mt++)
#pragma unroll
            for (int nt = 0; nt < 4; nt++)
                *(bf16x4*)&buf[wreg + (nt * 16 + lr) * S_R + mt * 16 + lq * 4] =
                    pack4(acc[mt][nt]);

        // ---- PV: C[d][i] = sum_j hT[d][j] * P[i][j]; pf built in halves ----
        f32x4 acc2[4][4];
#pragma unroll
        for (int mt = 0; mt < 4; mt++)
#pragma unroll
            for (int it = 0; it < 4; it++) acc2[mt][it] = (f32x4){0.f, 0.f, 0.f, 0.f};
        float f2v[4];
#pragma unroll
        for (int it = 0; it < 4; it++) f2v[it] = F2[w64 + it * 16 + lr];
#pragma unroll
        for (int kt = 0; kt < 2; kt++) {
            int j0 = kt * 32 + lq * 8;
            bf16x8 pf[4];
#pragma unroll
            for (int h = 0; h < 2; h++) {
                f32x4 f1h = *(const f32x4*)&F1[w64 + j0 + 4 * h];
                f32x4 lsh = *(const f32x4*)&LS[w64 + j0 + 4 * h];
#pragma unroll
                for (int it = 0; it < 4; it++) {
                    uint64_t mi = msk[it * 16 + lr];
                    uint32_t sh = ((uint32_t)(mi >> (kt * 32))) >> (lq * 8 + 4 * h);
#pragma unroll
                    for (int t = 0; t < 4; t++) {
                        float v = f2v[it] + f1h[t];
                        v = fmaxf(v, 0.2f * v);
                        float p = EXP2F(v - lsh[t]);
                        p = ((sh >> t) & 1u) ? p : 0.f;
                        pf[it][4 * h + t] = (__bf16)p;
                    }
                }
            }
#pragma unroll
            for (int mt = 0; mt < 4; mt++) {
                bf16x8 ha = *(const bf16x8*)&buf[wreg + (mt * 16 + lr) * S_R + kt * 32 + lq * 8];
#pragma unroll
                for (int it = 0; it < 4; it++)
                    acc2[mt][it] = __builtin_amdgcn_mfma_f32_16x16x32_bf16(
                        ha, pf[it], acc2[mt][it], 0, 0, 0);
            }
        }

        // ---- ELU epilogue -> own region as hout block (node-major); the
        //      own-region hT is dead (wave-local order), no barrier needed.
#pragma unroll
        for (int mt = 0; mt < 4; mt++)
#pragma unroll
            for (int it = 0; it < 4; it++) {
                int i = it * 16 + lr;
                f32x4 e;
#pragma unroll
                for (int r = 0; r < 4; r++) {
                    float v = acc2[mt][it][r];
                    e[r] = v > 0.f ? v : EXP2F(v * LOG2E) - 1.f;
                }
                if (i < N_)
                    *(bf16x4*)&buf[wreg + i * S_R + mt * 16 + lq * 4] = pack4(e);
            }
        // zero pad rows 62,63 of own region
        if (lane < 16) {
            uint4 z = {0u, 0u, 0u, 0u};
            *(uint4*)&buf[wreg + (N_ + (lane >> 3)) * S_R + (lane & 7) * 8] = z;
        }
        __syncthreads();   // (C) hout complete, regions shared again
    }

    // ---- pool + logits + log_softmax ----
    {
        float s = 0.f;
#pragma unroll 2
        for (int n = 0; n < N_; n++)
            s += bf2f(buf[(tid >> 6) * RSZ + n * S_R + (tid & 63)]);
        fstat[tid] = s;
    }
    __syncthreads();
    if (tid < 192) {
        int c = tid >> 6, ln = tid & 63;
        float p = 0.f;
#pragma unroll
        for (int k = ln; k < HID_; k += 64) p += fstat[k] * Wout[k * 3 + c];
        for (int off = 32; off > 0; off >>= 1) p += __shfl_down(p, off, 64);
        if (ln == 0) fstat[1536 + c] = p + bout[c];
    }
    __syncthreads();
    if (tid == 0) {
        float l0 = fstat[1536], l1 = fstat[1537], l2 = fstat[1538];
        float mm = fmaxf(l0, fmaxf(l1, l2));
        float s = __expf(l0 - mm) + __expf(l1 - mm) + __expf(l2 - mm);
        float ls = mm + logf(s);
        out[b * 3 + 0] = l0 - ls;
        out[b * 3 + 1] = l1 - ls;
        out[b * 3 + 2] = l2 - ls;
    }
}

// ---------------------------------------------------------------------------
extern "C" void kernel_launch(void* const* d_in, const int* in_sizes, int n_in,
                              void* d_out, int out_size, void* d_ws, size_t ws_size,
                              hipStream_t stream)
{
    const float* x   = (const float*)d_in[0];
    const int*   adj = (const int*)d_in[1];
    const float* bng = (const float*)d_in[2];
    const float* bnb = (const float*)d_in[3];
    const float* bnm = (const float*)d_in[4];
    const float* bnv = (const float*)d_in[5];
    const float* Wm  = (const float*)d_in[6];
    const float* bm  = (const float*)d_in[7];
    const float* Wg  = (const float*)d_in[8];
    const float* ag  = (const float*)d_in[9];
    const float* Wo  = (const float*)d_in[10];
    const float* bo  = (const float*)d_in[11];
    float* out = (float*)d_out;

    // ws layout: masks | masksT | wmlp_t | wgat2   (~4.2 MB)
    uint64_t* masks  = (uint64_t*)d_ws;
    uint64_t* masksT = masks + (size_t)B_ * 64;
    u16* wmlp_t = (u16*)(masksT + (size_t)B_ * 64);
    u16* wgat2  = wmlp_t + (size_t)HID_ * FIN_;

    int rep_total = HID_ * FIN_ + LAYERS_ * HEADS_ * 80 * HID_;  // 1048576
    repack_w<<<(rep_total + 255) / 256, 256, 0, stream>>>(Wm, Wg, ag, wmlp_t, wgat2);
    build_masks<<<B_, 256, 0, stream>>>(adj, masks, masksT);

    gat_fused<<<B_, 512, 0, stream>>>(
        x, bng, bnb, bnm, bnv, wmlp_t, bm, wgat2,
        masks, masksT, Wo, bo, out);
}

// Round 7
// 622.524 us; speedup vs baseline: 1.1691x; 1.1691x over previous
//
#include <hip/hip_runtime.h>
#include <cstdint>
#include <cstddef>

#define B_ 2048
#define N_ 62
#define FIN_ 128
#define HID_ 512
#define HEADS_ 8
#define FOUT_ 64
#define LAYERS_ 3
#define M_ (B_*N_)

typedef __bf16 bf16x8 __attribute__((ext_vector_type(8)));
typedef __bf16 bf16x4 __attribute__((ext_vector_type(4)));
typedef float  f32x4  __attribute__((ext_vector_type(4)));
typedef unsigned short u16;

#define LOG2E 1.4426950408889634f

#if __has_builtin(__builtin_amdgcn_exp2f)
#define EXP2F(x) __builtin_amdgcn_exp2f(x)
#else
#define EXP2F(x) exp2f(x)
#endif
#if __has_builtin(__builtin_amdgcn_logf)
#define LOG2F(x) __builtin_amdgcn_logf(x)
#else
#define LOG2F(x) log2f(x)
#endif

static __device__ __forceinline__ u16 f2bf(float f) {
    union { float f; uint32_t u; } v; v.f = f;
    uint32_t u = v.u;
    return (u16)((u + 0x7fffu + ((u >> 16) & 1u)) >> 16);
}
static __device__ __forceinline__ float bf2f(u16 s) {
    union { uint32_t u; float f; } v; v.u = ((uint32_t)s) << 16;
    return v.f;
}
static __device__ __forceinline__ float rdlane(float v, int l) {
    union { float f; int i; } a, b; a.f = v;
    b.i = __builtin_amdgcn_readlane(a.i, l);
    return b.f;
}
// compiler-friendly pack: emits v_cvt_pk_bf16_f32 pairs (RNE)
static __device__ __forceinline__ bf16x4 pack4(f32x4 v) {
    bf16x4 o;
    o[0] = (__bf16)v[0]; o[1] = (__bf16)v[1];
    o[2] = (__bf16)v[2]; o[3] = (__bf16)v[3];
    return o;
}

// ---------------------------------------------------------------------------
// Pack weights:
//  wmlp_t[n][k]  (n = feature 0..511, k = 0..127), bf16
//  wgat2[l][h][64][512]: row d = W_head^T (col k).  (f1/f2 are computed
//  in-register from the projection accumulator; no wa rows needed.)
// ---------------------------------------------------------------------------
__global__ __launch_bounds__(256) void repack_w(
    const float* __restrict__ Wm, const float* __restrict__ Wg,
    u16* __restrict__ wmlp_t, u16* __restrict__ wgat2)
{
    int idx = blockIdx.x * 256 + threadIdx.x;
    const int T1 = HID_ * FIN_;                    // 65536
    const int T2 = LAYERS_ * HEADS_ * 64 * HID_;   // 786432
    if (idx < T1) {
        int n = idx / FIN_, k = idx % FIN_;
        wmlp_t[idx] = f2bf(Wm[k * HID_ + n]);
    } else if (idx < T1 + T2) {
        int j = idx - T1;
        int lh = j / (64 * HID_);
        int r  = j % (64 * HID_);
        int n = r / HID_, k = r % HID_;
        wgat2[j] = f2bf(Wg[((size_t)lh * HID_ + k) * FOUT_ + n]);
    }
}

// ---------------------------------------------------------------------------
// adjacency -> per-row 64-bit masks + transposed (per-column) masks
// ---------------------------------------------------------------------------
__global__ __launch_bounds__(256) void build_masks(
    const int* __restrict__ adj, uint64_t* __restrict__ masks,
    uint64_t* __restrict__ masksT)
{
    __shared__ uint32_t m32[128];
    const int b = blockIdx.x, tid = threadIdx.x;
    if (tid < 128) m32[tid] = 0;
    __syncthreads();
    const int* a = adj + (size_t)b * N_ * N_;
    for (int idx = tid; idx < N_ * N_; idx += 256) {
        int i = idx / N_, j = idx % N_;
        if (a[idx] > 0) atomicOr(&m32[i * 2 + (j >> 5)], 1u << (j & 31));
    }
    __syncthreads();
    if (tid < 128) ((uint32_t*)(masks + (size_t)b * 64))[tid] = m32[tid];
    if (tid < 64) {
        int j = tid;
        uint64_t c = 0;
        for (int i = 0; i < N_; i++) {
            uint64_t bit = (m32[i * 2 + (j >> 5)] >> (j & 31)) & 1u;
            c |= bit << i;
        }
        masksT[(size_t)b * 64 + j] = c;
    }
}

// ---------------------------------------------------------------------------
// Fully fused network, one block per graph, wave = head.
// Register budget: __launch_bounds__(512,4) => 128 unified/wave; the 64-reg
// accumulator pins arch VGPRs to 64, so EVERY phase must keep arch-side
// pressure < 64 (round-6 post-mortem: deep unroll prefetch windows spilled).
//   proj (unroll 1) -> f1/f2 in-reg (128 FMA + lr-butterfly) -> F1/F2
//   -> bar(A) -> hT store (acc dies) -> stats -> PV -> ELU -> bar(C)
// ---------------------------------------------------------------------------
#define S_R  72      // u16 stride inside a region
#define RSZ  4608    // u16 size of a region (64*72)
#define S_X  136     // u16 stride for x-stage [64][S_X]
#define X0   27648   // u16 offset of x-stage (regions 6,7)

__global__ __launch_bounds__(512, 4) void gat_fused(
    const float* __restrict__ x,
    const float* __restrict__ bng, const float* __restrict__ bnb,
    const float* __restrict__ bnm, const float* __restrict__ bnv,
    const u16* __restrict__ wmlp_t, const float* __restrict__ bm,
    const u16* __restrict__ wgat2, const float* __restrict__ ag,
    const uint64_t* __restrict__ masks, const uint64_t* __restrict__ masksT,
    const float* __restrict__ Wout, const float* __restrict__ bout,
    float* __restrict__ out)
{
    __shared__ __align__(16) u16 buf[36864];
    __shared__ uint64_t msk[64];
    __shared__ __align__(16) float fstat[1544];
    float* F1 = fstat;          // [8][64] f1 per (head, j)  (log2e-scaled)
    float* F2 = fstat + 512;    // [8][64] f2 per (head, i)
    float* LS = fstat + 1024;   // [8][64] m + log2(s) per (head, j)

    const int tid = threadIdx.x, b = blockIdx.x;
    const int wave = tid >> 6, lane = tid & 63;
    const int lr = lane & 15, lq = lane >> 4;
    const int w64 = wave * 64;
    const int wreg = wave * RSZ;

    // per-lane transposed column mask (bit i = adj[i][lane])
    const uint64_t cm = masksT[(size_t)b * 64 + lane];
    const uint32_t cml = (uint32_t)cm, cmh = (uint32_t)(cm >> 32);

    // ---- stage BN(x) -> xs bf16 [64][136] (rows 62,63 zero); stage msk ----
    {
        const float* xg = x + (size_t)b * N_ * FIN_;
        for (int idx = tid; idx < 2048; idx += 512) {
            int n = idx >> 5, kq = idx & 31;
            bf16x4 o = {(__bf16)0.f, (__bf16)0.f, (__bf16)0.f, (__bf16)0.f};
            if (n < N_) {
                float s = bng[n] * rsqrtf(bnv[n] + 1e-5f);
                float sh = bnb[n] - bnm[n] * s;
                float4 v = *(const float4*)(xg + n * FIN_ + kq * 4);
                o[0] = (__bf16)(v.x * s + sh); o[1] = (__bf16)(v.y * s + sh);
                o[2] = (__bf16)(v.z * s + sh); o[3] = (__bf16)(v.w * s + sh);
            }
            *(bf16x4*)&buf[X0 + n * S_X + kq * 4] = o;
        }
        if (tid < 64) msk[tid] = (tid < N_) ? masks[(size_t)b * 64 + tid] : 0ull;
    }
    __syncthreads();

    // ---- MLP (operand-swapped): C[feature][node]; feature block w -> region w
    {
        f32x4 acc[4][4];
#pragma unroll
        for (int mt = 0; mt < 4; mt++)
#pragma unroll
            for (int nt = 0; nt < 4; nt++) acc[mt][nt] = (f32x4){0.f, 0.f, 0.f, 0.f};
        const int c0 = w64;
#pragma unroll 1
        for (int kt = 0; kt < 4; kt++) {
            int k0 = kt * 32;
            bf16x8 xf[4];
#pragma unroll
            for (int nt = 0; nt < 4; nt++)
                xf[nt] = *(const bf16x8*)&buf[X0 + (nt * 16 + lr) * S_X + k0 + lq * 8];
#pragma unroll
            for (int mt = 0; mt < 4; mt++) {
                bf16x8 wf = *(const bf16x8*)(wmlp_t + (size_t)(c0 + mt * 16 + lr) * FIN_ + k0 + lq * 8);
#pragma unroll
                for (int nt = 0; nt < 4; nt++)
                    acc[mt][nt] = __builtin_amdgcn_mfma_f32_16x16x32_bf16(
                        wf, xf[nt], acc[mt][nt], 0, 0, 0);
            }
        }
        __syncthreads();   // xs reads done before region writes (waves 6,7 alias xs)
        f32x4 bl[4];
#pragma unroll
        for (int mt = 0; mt < 4; mt++)
            bl[mt] = *(const f32x4*)&bm[c0 + mt * 16 + lq * 4];
#pragma unroll
        for (int mt = 0; mt < 4; mt++)
#pragma unroll
            for (int nt = 0; nt < 4; nt++) {
                int node = nt * 16 + lr;
                if (node < N_)
                    *(bf16x4*)&buf[wreg + node * S_R + mt * 16 + lq * 4] =
                        pack4(acc[mt][nt] + bl[mt]);
            }
        // zero pad rows 62,63 of own region
        if (lane < 16) {
            uint4 z = {0u, 0u, 0u, 0u};
            *(uint4*)&buf[wreg + (N_ + (lane >> 3)) * S_R + (lane & 7) * 8] = z;
        }
    }
    __syncthreads();

    // ---- GAT layers ----
#pragma unroll 1
    for (int l = 0; l < LAYERS_; l++) {
        const u16* wp = wgat2 + (size_t)(l * HEADS_ + wave) * 64 * HID_;

        // ---- main projection: h = hin @ W_head (64x512 @ 512x64) ----
        // acc[mt][nt][r] = h[node = mt*16+lq*4+r][d = nt*16+lr]
        f32x4 acc[4][4];
#pragma unroll
        for (int mt = 0; mt < 4; mt++)
#pragma unroll
            for (int nt = 0; nt < 4; nt++) acc[mt][nt] = (f32x4){0.f, 0.f, 0.f, 0.f};
#pragma unroll 1
        for (int kt = 0; kt < 16; kt++) {
            int koff = (kt >> 1) * RSZ + (kt & 1) * 32 + lq * 8;
            bf16x8 af[4];
#pragma unroll
            for (int mt = 0; mt < 4; mt++)
                af[mt] = *(const bf16x8*)&buf[koff + (mt * 16 + lr) * S_R];
#pragma unroll
            for (int nt = 0; nt < 4; nt++) {
                bf16x8 bfr = *(const bf16x8*)(wp + (size_t)(nt * 16 + lr) * HID_ + kt * 32 + lq * 8);
#pragma unroll
                for (int mt = 0; mt < 4; mt++)
                    acc[mt][nt] = __builtin_amdgcn_mfma_f32_16x16x32_bf16(
                        af[mt], bfr, acc[mt][nt], 0, 0, 0);
            }
        }

        // ---- f1/f2 in-register from acc (no LDS reads, no extra MFMA) ----
        // f[node] = sum_d h[node][d]*a[d]; lane holds d = nt*16+lr, so each
        // lane makes 16 (mt,r)-partials, then a 4-step halving butterfly over
        // the 16-lane lr group lands combo lr in lane lr (compile-time idx).
        {
            float a1v[4], a2v[4];
            const float* agl = ag + (size_t)(l * HEADS_ + wave) * 128;
#pragma unroll
            for (int nt = 0; nt < 4; nt++) {
                a1v[nt] = agl[nt * 16 + lr] * LOG2E;
                a2v[nt] = agl[64 + nt * 16 + lr] * LOG2E;
            }
            float p1v[16], p2v[16];
#pragma unroll
            for (int mt = 0; mt < 4; mt++)
#pragma unroll
                for (int r = 0; r < 4; r++) {
                    float s1 = 0.f, s2 = 0.f;
#pragma unroll
                    for (int nt = 0; nt < 4; nt++) {
                        float hv = acc[mt][nt][r];
                        s1 = fmaf(hv, a1v[nt], s1);
                        s2 = fmaf(hv, a2v[nt], s2);
                    }
                    p1v[mt * 4 + r] = s1;
                    p2v[mt * 4 + r] = s2;
                }
#pragma unroll
            for (int c = 0; c < 8; c++) {
                float tA = __shfl_xor(p1v[c], 8, 64);
                float tB = __shfl_xor(p1v[c + 8], 8, 64);
                p1v[c] = (lr & 8) ? (p1v[c + 8] + tB) : (p1v[c] + tA);
                float uA = __shfl_xor(p2v[c], 8, 64);
                float uB = __shfl_xor(p2v[c + 8], 8, 64);
                p2v[c] = (lr & 8) ? (p2v[c + 8] + uB) : (p2v[c] + uA);
            }
#pragma unroll
            for (int c = 0; c < 4; c++) {
                float tA = __shfl_xor(p1v[c], 4, 64);
                float tB = __shfl_xor(p1v[c + 4], 4, 64);
                p1v[c] = (lr & 4) ? (p1v[c + 4] + tB) : (p1v[c] + tA);
                float uA = __shfl_xor(p2v[c], 4, 64);
                float uB = __shfl_xor(p2v[c + 4], 4, 64);
                p2v[c] = (lr & 4) ? (p2v[c + 4] + uB) : (p2v[c] + uA);
            }
#pragma unroll
            for (int c = 0; c < 2; c++) {
                float tA = __shfl_xor(p1v[c], 2, 64);
                float tB = __shfl_xor(p1v[c + 2], 2, 64);
                p1v[c] = (lr & 2) ? (p1v[c + 2] + tB) : (p1v[c] + tA);
                float uA = __shfl_xor(p2v[c], 2, 64);
                float uB = __shfl_xor(p2v[c + 2], 2, 64);
                p2v[c] = (lr & 2) ? (p2v[c + 2] + uB) : (p2v[c] + uA);
            }
            {
                float tA = __shfl_xor(p1v[0], 1, 64);
                float tB = __shfl_xor(p1v[1], 1, 64);
                float f1fin = (lr & 1) ? (p1v[1] + tB) : (p1v[0] + tA);
                float uA = __shfl_xor(p2v[0], 1, 64);
                float uB = __shfl_xor(p2v[1], 1, 64);
                float f2fin = (lr & 1) ? (p2v[1] + uB) : (p2v[0] + uA);
                int node = (lr >> 2) * 16 + lq * 4 + (lr & 3);
                F1[w64 + node] = f1fin;
                F2[w64 + node] = f2fin;
            }
        }

        __syncthreads();   // (A) all hin reads done -> regions become wave-private

        // transpose-store h -> own region as hT[d_local][j] (stride 72);
        // acc fully dead after this.
#pragma unroll
        for (int mt = 0; mt < 4; mt++)
#pragma unroll
            for (int nt = 0; nt < 4; nt++)
                *(bf16x4*)&buf[wreg + (nt * 16 + lr) * S_R + mt * 16 + lq * 4] =
                    pack4(acc[mt][nt]);

        // ---- stats (wave-local: own F1/F2 -> own LS) ----
        {
            float p1 = F1[w64 + lane];
            float p2 = F2[w64 + lane];
            // m_j = leaky(max_all_i f2_i + f1_j): upper bound, exact for
            // softmax (m-invariance). 6-step wave max.
            float pm = (lane < N_) ? p2 : -3.0e38f;
#pragma unroll
            for (int off = 32; off; off >>= 1) pm = fmaxf(pm, __shfl_xor(pm, off, 64));
            float vm = pm + p1;
            float m = fmaxf(vm, 0.2f * vm);
            float s0 = 0.f, s1 = 0.f;
#pragma unroll
            for (int i = 0; i < N_; i += 2) {
                float fa = rdlane(p2, i), fb = rdlane(p2, i + 1);
                float va = fa + p1, vb = fb + p1;
                va = fmaxf(va, 0.2f * va); vb = fmaxf(vb, 0.2f * vb);
                float ea = EXP2F(va - m), eb = EXP2F(vb - m);
                uint32_t w = (i < 32) ? cml : cmh;
                s0 += ((w >> (i & 31)) & 1u) ? ea : 0.f;
                s1 += ((w >> ((i + 1) & 31)) & 1u) ? eb : 0.f;
            }
            float ssum = fmaxf(s0 + s1, 1e-35f);
            LS[w64 + lane] = m + LOG2F(ssum);   // p = exp2(e - LS)
        }

        // ---- PV: C[d][i] = sum_j hT[d][j] * P[i][j]; pf built in halves ----
        f32x4 acc2[4][4];
#pragma unroll
        for (int mt = 0; mt < 4; mt++)
#pragma unroll
            for (int it = 0; it < 4; it++) acc2[mt][it] = (f32x4){0.f, 0.f, 0.f, 0.f};
        float f2v[4];
#pragma unroll
        for (int it = 0; it < 4; it++) f2v[it] = F2[w64 + it * 16 + lr];
#pragma unroll
        for (int kt = 0; kt < 2; kt++) {
            int j0 = kt * 32 + lq * 8;
            bf16x8 pf[4];
#pragma unroll
            for (int h = 0; h < 2; h++) {
                f32x4 f1h = *(const f32x4*)&F1[w64 + j0 + 4 * h];
                f32x4 lsh = *(const f32x4*)&LS[w64 + j0 + 4 * h];
#pragma unroll
                for (int it = 0; it < 4; it++) {
                    uint64_t mi = msk[it * 16 + lr];
                    uint32_t sh = ((uint32_t)(mi >> (kt * 32))) >> (lq * 8 + 4 * h);
#pragma unroll
                    for (int t = 0; t < 4; t++) {
                        float v = f2v[it] + f1h[t];
                        v = fmaxf(v, 0.2f * v);
                        float p = EXP2F(v - lsh[t]);
                        p = ((sh >> t) & 1u) ? p : 0.f;
                        pf[it][4 * h + t] = (__bf16)p;
                    }
                }
            }
#pragma unroll
            for (int mt = 0; mt < 4; mt++) {
                bf16x8 ha = *(const bf16x8*)&buf[wreg + (mt * 16 + lr) * S_R + kt * 32 + lq * 8];
#pragma unroll
                for (int it = 0; it < 4; it++)
                    acc2[mt][it] = __builtin_amdgcn_mfma_f32_16x16x32_bf16(
                        ha, pf[it], acc2[mt][it], 0, 0, 0);
            }
        }

        // ---- ELU epilogue -> own region as hout block (node-major); the
        //      own-region hT is dead (wave-local order), no barrier needed.
#pragma unroll
        for (int mt = 0; mt < 4; mt++)
#pragma unroll
            for (int it = 0; it < 4; it++) {
                int i = it * 16 + lr;
                f32x4 e;
#pragma unroll
                for (int r = 0; r < 4; r++) {
                    float v = acc2[mt][it][r];
                    e[r] = v > 0.f ? v : EXP2F(v * LOG2E) - 1.f;
                }
                if (i < N_)
                    *(bf16x4*)&buf[wreg + i * S_R + mt * 16 + lq * 4] = pack4(e);
            }
        // zero pad rows 62,63 of own region
        if (lane < 16) {
            uint4 z = {0u, 0u, 0u, 0u};
            *(uint4*)&buf[wreg + (N_ + (lane >> 3)) * S_R + (lane & 7) * 8] = z;
        }
        __syncthreads();   // (C) hout complete, regions shared again
    }

    // ---- pool + logits + log_softmax ----
    {
        float s = 0.f;
#pragma unroll 2
        for (int n = 0; n < N_; n++)
            s += bf2f(buf[(tid >> 6) * RSZ + n * S_R + (tid & 63)]);
        fstat[tid] = s;
    }
    __syncthreads();
    if (tid < 192) {
        int c = tid >> 6, ln = tid & 63;
        float p = 0.f;
#pragma unroll
        for (int k = ln; k < HID_; k += 64) p += fstat[k] * Wout[k * 3 + c];
        for (int off = 32; off > 0; off >>= 1) p += __shfl_down(p, off, 64);
        if (ln == 0) fstat[1536 + c] = p + bout[c];
    }
    __syncthreads();
    if (tid == 0) {
        float l0 = fstat[1536], l1 = fstat[1537], l2 = fstat[1538];
        float mm = fmaxf(l0, fmaxf(l1, l2));
        float s = __expf(l0 - mm) + __expf(l1 - mm) + __expf(l2 - mm);
        float ls = mm + logf(s);
        out[b * 3 + 0] = l0 - ls;
        out[b * 3 + 1] = l1 - ls;
        out[b * 3 + 2] = l2 - ls;
    }
}

// ---------------------------------------------------------------------------
extern "C" void kernel_launch(void* const* d_in, const int* in_sizes, int n_in,
                              void* d_out, int out_size, void* d_ws, size_t ws_size,
                              hipStream_t stream)
{
    const float* x   = (const float*)d_in[0];
    const int*   adj = (const int*)d_in[1];
    const float* bng = (const float*)d_in[2];
    const float* bnb = (const float*)d_in[3];
    const float* bnm = (const float*)d_in[4];
    const float* bnv = (const float*)d_in[5];
    const float* Wm  = (const float*)d_in[6];
    const float* bm  = (const float*)d_in[7];
    const float* Wg  = (const float*)d_in[8];
    const float* ag  = (const float*)d_in[9];
    const float* Wo  = (const float*)d_in[10];
    const float* bo  = (const float*)d_in[11];
    float* out = (float*)d_out;

    // ws layout: masks | masksT | wmlp_t | wgat2   (~3.8 MB)
    uint64_t* masks  = (uint64_t*)d_ws;
    uint64_t* masksT = masks + (size_t)B_ * 64;
    u16* wmlp_t = (u16*)(masksT + (size_t)B_ * 64);
    u16* wgat2  = wmlp_t + (size_t)HID_ * FIN_;

    int rep_total = HID_ * FIN_ + LAYERS_ * HEADS_ * 64 * HID_;  // 851968
    repack_w<<<(rep_total + 255) / 256, 256, 0, stream>>>(Wm, Wg, wmlp_t, wgat2);
    build_masks<<<B_, 256, 0, stream>>>(adj, masks, masksT);

    gat_fused<<<B_, 512, 0, stream>>>(
        x, bng, bnb, bnm, bnv, wmlp_t, bm, wgat2, ag,
        masks, masksT, Wo, bo, out);
}